// Round 4
// baseline (385.347 us; speedup 1.0000x reference)
//
#include <hip/hip_runtime.h>
#include <hip/hip_bf16.h>

#define N_NODES_C 100000
#define FEATS 128
#define SH 10             // bucket shift: 1024 nodes per bucket
#define NBK 128           // padded bucket count (active: 98)
#define PB  256           // partition blocks
#define CAST_BLOCKS 12500 // (100000*128/4)/256

typedef unsigned int uint32;
typedef __bf16 bf16_t;
typedef bf16_t bf16x8 __attribute__((ext_vector_type(8)));
typedef float f32x4 __attribute__((ext_vector_type(4)));

union Frag { uint4 u; bf16x8 v; };

__device__ __forceinline__ unsigned short f32_to_bf16_bits(float f) {
    uint32 u = __float_as_uint(f);
    u += 0x7fffu + ((u >> 16) & 1u);   // round-to-nearest-even (finite values)
    return (unsigned short)(u >> 16);
}
__device__ __forceinline__ float bf16_lo(uint32 p) { return __uint_as_float(p << 16); }
__device__ __forceinline__ float bf16_hi(uint32 p) { return __uint_as_float(p & 0xffff0000u); }

// ---------------- Fused prep: part_count + wtprep x2 + cast ----------------
__global__ __launch_bounds__(256) void prep_fused(
    const int* __restrict__ dst, int* __restrict__ gHist, int nE, int chunk,
    const float4* __restrict__ emb4, unsigned short* __restrict__ hb0, int n4,
    const float* __restrict__ W1s, const float* __restrict__ W1n, unsigned short* __restrict__ wt1,
    const float* __restrict__ W2s, const float* __restrict__ W2n, unsigned short* __restrict__ wt2)
{
    __shared__ int h[NBK];
    const int b = blockIdx.x;
    const int tid = threadIdx.x;

    if (b < PB) {
        // --- bucket histogram over this block's edge chunk ---
        if (tid < NBK) h[tid] = 0;
        __syncthreads();
        const int b0 = b * chunk;
        const int e1 = min(b0 + chunk, nE);
        for (int e = b0 + tid; e < e1; e += 256)
            atomicAdd(&h[dst[e] >> SH], 1);
        __syncthreads();
        if (tid < NBK) gHist[tid * PB + b] = h[tid];
    } else if (b < PB + 32) {
        // --- weight pre-swizzle into B-fragment order ---
        // wt[(f*64+l)*8+j] = W[k][n], f=nt*8+ks, n=nt*16+(l&15), k=ks*32+(l>>4)*8+j
        const int which = (b - PB) >> 4;                 // 0 -> layer1, 1 -> layer2
        const float* Ws = which ? W2s : W1s;
        const float* Wn = which ? W2n : W1n;
        unsigned short* wt = which ? wt2 : wt1;
        int gid = ((b - PB) & 15) * 256 + tid;           // 0..4095
        int frag = gid >> 6, lane = gid & 63;
        int nt = frag >> 3, ks = frag & 7;
        int n = nt * 16 + (lane & 15);
        int kbase = ks * 32 + (lane >> 4) * 8;
        union { unsigned short s[8]; uint4 u; } o;
#pragma unroll
        for (int j = 0; j < 8; ++j) {
            int k = kbase + j;
            float v = (k < 128) ? Ws[(size_t)k * FEATS + n] : Wn[(size_t)(k - 128) * FEATS + n];
            o.s[j] = f32_to_bf16_bits(v);
        }
        *(uint4*)(wt + (size_t)gid * 8) = o.u;
    } else {
        // --- fp32 -> bf16 node-table cast (row-major [N][128]) ---
        int i = (b - PB - 32) * 256 + tid;
        if (i >= n4) return;
        float4 v = emb4[i];
        union { unsigned short s[4]; uint2 u; } o;
        o.s[0] = f32_to_bf16_bits(v.x);
        o.s[1] = f32_to_bf16_bits(v.y);
        o.s[2] = f32_to_bf16_bits(v.z);
        o.s[3] = f32_to_bf16_bits(v.w);
        *(uint2*)(hb0 + (size_t)i * 4) = o.u;
    }
}

// ---------------- One-dispatch exclusive scan of gHist (32768 ints) ----------------
__global__ __launch_bounds__(1024) void scan_one(int* __restrict__ g) {
    __shared__ int ss[1024];
    const int tid = threadIdx.x;
    const int base = tid * 32;
    int pref[32];
    int sum = 0;
#pragma unroll
    for (int j = 0; j < 32; ++j) {
        int v = g[base + j];
        pref[j] = sum;
        sum += v;
    }
    ss[tid] = sum;
    __syncthreads();
    for (int d = 1; d < 1024; d <<= 1) {
        int t = (tid >= d) ? ss[tid - d] : 0;
        __syncthreads();
        ss[tid] += t;
        __syncthreads();
    }
    int ex = ss[tid] - sum;
#pragma unroll
    for (int j = 0; j < 32; ++j)
        g[base + j] = ex + pref[j];
}

// ---------------- P2: scatter packed (src | localdst<<17) into bucketed ebuf ----------------
// 1024 threads/block (R4): 256 blocks x 4 waves/SIMD-equivalent occupancy.
// Previously 256 threads = 1 wave/SIMD device-wide -> latency-bound with no TLP.
__global__ __launch_bounds__(1024) void part_scatter(const int* __restrict__ src,
                                                     const int* __restrict__ dst,
                                                     const int* __restrict__ gScan,
                                                     uint32* __restrict__ ebuf,
                                                     int nE, int chunk) {
    __shared__ int cur[NBK];
    const int tid = threadIdx.x;
    if (tid < NBK) cur[tid] = gScan[tid * PB + blockIdx.x];
    __syncthreads();
    const int b0 = blockIdx.x * chunk;
    const int e1 = min(b0 + chunk, nE);
    for (int e = b0 + tid; e < e1; e += 1024) {
        int d = dst[e];
        int pos = atomicAdd(&cur[d >> SH], 1);
        ebuf[pos] = (uint32)src[e] | ((uint32)(d & ((1 << SH) - 1)) << 17);
    }
}

// ---------------- P3: per-bucket CSR finalize ----------------
// csr stores src*256 = byte offset of the node's 256-B feature row (src < 2^17, fits 25 bits).
__global__ __launch_bounds__(1024) void bucket_csr(const uint32* __restrict__ ebuf,
                                                   const int* __restrict__ gScan,
                                                   int* __restrict__ off,
                                                   int* __restrict__ csr,
                                                   int nE) {
    __shared__ int cnt[1 << SH];
    __shared__ int ss[1 << SH];
    const int b = blockIdx.x;
    const int tid = threadIdx.x;
    const int start = gScan[b * PB];
    const int end = gScan[(b + 1) * PB];
    const int nodeBase = b << SH;
    cnt[tid] = 0;
    __syncthreads();
    for (int e = start + tid; e < end; e += 1024)
        atomicAdd(&cnt[ebuf[e] >> 17], 1);
    __syncthreads();
    int own = cnt[tid];
    ss[tid] = own;
    __syncthreads();
    for (int d = 1; d < 1024; d <<= 1) {
        int t = (tid >= d) ? ss[tid - d] : 0;
        __syncthreads();
        ss[tid] += t;
        __syncthreads();
    }
    int ex = ss[tid] - own;
    cnt[tid] = ex;                     // becomes placement cursor
    int node = nodeBase + tid;
    if (node < N_NODES_C) off[node] = start + ex;
    if (b == gridDim.x - 1 && tid == 0) off[N_NODES_C] = nE;
    __syncthreads();
    for (int e = start + tid; e < end; e += 1024) {
        uint32 p = ebuf[e];
        int pos = atomicAdd(&cnt[p >> 17], 1);
        csr[start + pos] = (int)((p & 0x1FFFFu) << 8);   // byte offset of src row
    }
}

// ---------------- Gather (mean aggregation over bf16 table) ----------------
// 4 nodes per 256-thread block; one wave per node; uint2 (8 B) per lane so one
// load instruction covers TWO edges' 256-B rows (lanes 0-31 = even edge,
// 32-63 = odd edge). Even/odd partials combined with shfl_xor(32) at the end.
// csr holds byte offsets (src*256): per-load address = one 64-bit add.
// Main loop unrolled to 16 edges (8 loads in flight) -> 2x MLP vs R3 (latency-bound).
// One wave per node keeps 100K waves in flight (do not re-fuse with GEMM; R4 regressed).
__global__ __launch_bounds__(256) void gather_mean_w2(const unsigned short* __restrict__ hb,
                                                      const int* __restrict__ csrB,
                                                      const int* __restrict__ off,
                                                      unsigned short* __restrict__ meanb,
                                                      int nNodes) {
    const int node = blockIdx.x * 4 + (threadIdx.x >> 6);
    const int lane = threadIdx.x & 63;
    if (node >= nNodes) return;
    const int start = __builtin_amdgcn_readfirstlane(off[node]);
    const int end   = __builtin_amdgcn_readfirstlane(off[node + 1]);
    const int half = lane >> 5;                 // which edge of a pair
    const int c = lane & 31;                    // uint2 column within 256-B row
    const char* base = (const char*)hb + (size_t)(c * 8);
    float a0 = 0.f, a1 = 0.f, a2 = 0.f, a3 = 0.f;
    int e = start;
    for (; e + 16 <= end; e += 16) {
        const int o0  = csrB[e + 0],  o1  = csrB[e + 1],  o2  = csrB[e + 2],  o3  = csrB[e + 3];
        const int o4  = csrB[e + 4],  o5  = csrB[e + 5],  o6  = csrB[e + 6],  o7  = csrB[e + 7];
        const int o8  = csrB[e + 8],  o9  = csrB[e + 9],  o10 = csrB[e + 10], o11 = csrB[e + 11];
        const int o12 = csrB[e + 12], o13 = csrB[e + 13], o14 = csrB[e + 14], o15 = csrB[e + 15];
        const uint2 u0 = *(const uint2*)(base + (size_t)(half ? o1  : o0));
        const uint2 u1 = *(const uint2*)(base + (size_t)(half ? o3  : o2));
        const uint2 u2 = *(const uint2*)(base + (size_t)(half ? o5  : o4));
        const uint2 u3 = *(const uint2*)(base + (size_t)(half ? o7  : o6));
        const uint2 u4 = *(const uint2*)(base + (size_t)(half ? o9  : o8));
        const uint2 u5 = *(const uint2*)(base + (size_t)(half ? o11 : o10));
        const uint2 u6 = *(const uint2*)(base + (size_t)(half ? o13 : o12));
        const uint2 u7 = *(const uint2*)(base + (size_t)(half ? o15 : o14));
        a0 += bf16_lo(u0.x); a1 += bf16_hi(u0.x); a2 += bf16_lo(u0.y); a3 += bf16_hi(u0.y);
        a0 += bf16_lo(u1.x); a1 += bf16_hi(u1.x); a2 += bf16_lo(u1.y); a3 += bf16_hi(u1.y);
        a0 += bf16_lo(u2.x); a1 += bf16_hi(u2.x); a2 += bf16_lo(u2.y); a3 += bf16_hi(u2.y);
        a0 += bf16_lo(u3.x); a1 += bf16_hi(u3.x); a2 += bf16_lo(u3.y); a3 += bf16_hi(u3.y);
        a0 += bf16_lo(u4.x); a1 += bf16_hi(u4.x); a2 += bf16_lo(u4.y); a3 += bf16_hi(u4.y);
        a0 += bf16_lo(u5.x); a1 += bf16_hi(u5.x); a2 += bf16_lo(u5.y); a3 += bf16_hi(u5.y);
        a0 += bf16_lo(u6.x); a1 += bf16_hi(u6.x); a2 += bf16_lo(u6.y); a3 += bf16_hi(u6.y);
        a0 += bf16_lo(u7.x); a1 += bf16_hi(u7.x); a2 += bf16_lo(u7.y); a3 += bf16_hi(u7.y);
    }
    if (e + 8 <= end) {
        const int o0 = csrB[e + 0], o1 = csrB[e + 1], o2 = csrB[e + 2], o3 = csrB[e + 3];
        const int o4 = csrB[e + 4], o5 = csrB[e + 5], o6 = csrB[e + 6], o7 = csrB[e + 7];
        const uint2 u0 = *(const uint2*)(base + (size_t)(half ? o1 : o0));
        const uint2 u1 = *(const uint2*)(base + (size_t)(half ? o3 : o2));
        const uint2 u2 = *(const uint2*)(base + (size_t)(half ? o5 : o4));
        const uint2 u3 = *(const uint2*)(base + (size_t)(half ? o7 : o6));
        a0 += bf16_lo(u0.x); a1 += bf16_hi(u0.x); a2 += bf16_lo(u0.y); a3 += bf16_hi(u0.y);
        a0 += bf16_lo(u1.x); a1 += bf16_hi(u1.x); a2 += bf16_lo(u1.y); a3 += bf16_hi(u1.y);
        a0 += bf16_lo(u2.x); a1 += bf16_hi(u2.x); a2 += bf16_lo(u2.y); a3 += bf16_hi(u2.y);
        a0 += bf16_lo(u3.x); a1 += bf16_hi(u3.x); a2 += bf16_lo(u3.y); a3 += bf16_hi(u3.y);
        e += 8;
    }
    if (e + 4 <= end) {
        const int o0 = csrB[e + 0], o1 = csrB[e + 1], o2 = csrB[e + 2], o3 = csrB[e + 3];
        const uint2 u0 = *(const uint2*)(base + (size_t)(half ? o1 : o0));
        const uint2 u1 = *(const uint2*)(base + (size_t)(half ? o3 : o2));
        a0 += bf16_lo(u0.x); a1 += bf16_hi(u0.x); a2 += bf16_lo(u0.y); a3 += bf16_hi(u0.y);
        a0 += bf16_lo(u1.x); a1 += bf16_hi(u1.x); a2 += bf16_lo(u1.y); a3 += bf16_hi(u1.y);
        e += 4;
    }
    if (e + 2 <= end) {
        const int o0 = csrB[e + 0], o1 = csrB[e + 1];
        const uint2 u = *(const uint2*)(base + (size_t)(half ? o1 : o0));
        a0 += bf16_lo(u.x); a1 += bf16_hi(u.x); a2 += bf16_lo(u.y); a3 += bf16_hi(u.y);
        e += 2;
    }
    if (e < end && half == 0) {
        const uint2 u = *(const uint2*)(base + (size_t)csrB[e]);
        a0 += bf16_lo(u.x); a1 += bf16_hi(u.x); a2 += bf16_lo(u.y); a3 += bf16_hi(u.y);
    }
    // combine even-edge / odd-edge partial sums held in lane pairs (l, l^32)
    a0 += __shfl_xor(a0, 32);
    a1 += __shfl_xor(a1, 32);
    a2 += __shfl_xor(a2, 32);
    a3 += __shfl_xor(a3, 32);
    const int deg = end - start;
    const float invd = (deg > 0) ? (1.f / (float)deg) : 0.f;
    if (half == 0) {
        uint2 o;
        o.x = ((uint32)f32_to_bf16_bits(a1 * invd) << 16) | (uint32)f32_to_bf16_bits(a0 * invd);
        o.y = ((uint32)f32_to_bf16_bits(a3 * invd) << 16) | (uint32)f32_to_bf16_bits(a2 * invd);
        ((uint2*)meanb)[(size_t)node * 32 + c] = o;
    }
}

// ---------------- MFMA SAGE GEMM (LDS-free) ----------------
// Per wave: 32-row stripe x 128 cols, K=256 = [HB | MB]. Two 16-row groups
// share each B-fragment load (R4): halves per-output-row B traffic from L1/L2.
__global__ __launch_bounds__(256) void sage_gemm_mfma(const unsigned short* __restrict__ HB,
                                                      const unsigned short* __restrict__ MB,
                                                      const unsigned short* __restrict__ WT,
                                                      const float* __restrict__ bias,
                                                      void* __restrict__ OUTP,
                                                      int nNodes, int mode) {
    const int wave = threadIdx.x >> 6;
    const int lane = threadIdx.x & 63;
    const int waveBase = blockIdx.x * 128 + wave * 32;
    const int m = lane & 15;
    const int quad = lane >> 4;

    int arow0 = waveBase + m;
    int arow1 = waveBase + 16 + m;
    if (arow0 >= nNodes) arow0 = nNodes - 1;         // clamp loads; stores guarded below
    if (arow1 >= nNodes) arow1 = nNodes - 1;
    const uint4* hrow0 = (const uint4*)(HB + (size_t)arow0 * FEATS);
    const uint4* mrow0 = (const uint4*)(MB + (size_t)arow0 * FEATS);
    const uint4* hrow1 = (const uint4*)(HB + (size_t)arow1 * FEATS);
    const uint4* mrow1 = (const uint4*)(MB + (size_t)arow1 * FEATS);

    Frag a0[8], a1[8];
#pragma unroll
    for (int ks = 0; ks < 4; ++ks) a0[ks].u = hrow0[ks * 4 + quad];
#pragma unroll
    for (int ks = 0; ks < 4; ++ks) a0[ks + 4].u = mrow0[ks * 4 + quad];
#pragma unroll
    for (int ks = 0; ks < 4; ++ks) a1[ks].u = hrow1[ks * 4 + quad];
#pragma unroll
    for (int ks = 0; ks < 4; ++ks) a1[ks + 4].u = mrow1[ks * 4 + quad];

    const uint4* wt4 = (const uint4*)WT;
    f32x4 acc0[8], acc1[8];
#pragma unroll
    for (int nt = 0; nt < 8; ++nt) {
        acc0[nt] = (f32x4){0.f, 0.f, 0.f, 0.f};
        acc1[nt] = (f32x4){0.f, 0.f, 0.f, 0.f};
    }

#pragma unroll
    for (int ks = 0; ks < 8; ++ks) {
#pragma unroll
        for (int nt = 0; nt < 8; ++nt) {
            Frag b;
            b.u = wt4[(size_t)(nt * 8 + ks) * 64 + lane];
            acc0[nt] = __builtin_amdgcn_mfma_f32_16x16x32_bf16(a0[ks].v, b.v, acc0[nt], 0, 0, 0);
            acc1[nt] = __builtin_amdgcn_mfma_f32_16x16x32_bf16(a1[ks].v, b.v, acc1[nt], 0, 0, 0);
        }
    }

#pragma unroll
    for (int nt = 0; nt < 8; ++nt) {
        const int col = nt * 16 + m;
        const float bv = bias[col];
#pragma unroll
        for (int r = 0; r < 4; ++r) {
            // C/D: row=(lane>>4)*4+reg, col=lane&15
            const int g0 = waveBase + quad * 4 + r;
            const int g1 = waveBase + 16 + quad * 4 + r;
            if (g0 < nNodes) {
                float v = acc0[nt][r] + bv;
                if (mode) {
                    v = v > 0.f ? v : 0.2f * v;
                    ((unsigned short*)OUTP)[(size_t)g0 * FEATS + col] = f32_to_bf16_bits(v);
                } else {
                    ((float*)OUTP)[(size_t)g0 * FEATS + col] = v;
                }
            }
            if (g1 < nNodes) {
                float v = acc1[nt][r] + bv;
                if (mode) {
                    v = v > 0.f ? v : 0.2f * v;
                    ((unsigned short*)OUTP)[(size_t)g1 * FEATS + col] = f32_to_bf16_bits(v);
                } else {
                    ((float*)OUTP)[(size_t)g1 * FEATS + col] = v;
                }
            }
        }
    }
}

extern "C" void kernel_launch(void* const* d_in, const int* in_sizes, int n_in,
                              void* d_out, int out_size, void* d_ws, size_t ws_size,
                              hipStream_t stream) {
    const float* emb = (const float*)d_in[0];
    const float* W1s = (const float*)d_in[1];
    const float* W1n = (const float*)d_in[2];
    const float* b1  = (const float*)d_in[3];
    const float* W2s = (const float*)d_in[4];
    const float* W2n = (const float*)d_in[5];
    const float* b2  = (const float*)d_in[6];
    const int*   edg = (const int*)d_in[7];

    const int nE = in_sizes[7] / 2;
    const int* src = edg;
    const int* dst = edg + nE;

    const int chunk = (nE + PB - 1) / PB;            // 6250
    const int nActB = (N_NODES_C + (1 << SH) - 1) >> SH;   // 98
    const int n4 = N_NODES_C * FEATS / 4;            // 3,200,000

    const size_t bfTab = (size_t)N_NODES_C * FEATS * sizeof(unsigned short);  // 25.6 MB

    char* ws = (char*)d_ws;
    int* off      = (int*)(ws);                      // 400 KB + 4
    int* gHist    = (int*)(ws + (512 << 10));        // 128 KB
    int* csr      = (int*)(ws + (1 << 20));          // 6.4 MB
    uint32* ebuf  = (uint32*)(ws + (8 << 20));       // 6.4 MB
    unsigned short* wt1 = (unsigned short*)(ws + (15 << 20));   // 64 KB
    unsigned short* wt2 = (unsigned short*)(ws + (15 << 20) + (64 << 10));
    unsigned short* hb0 = (unsigned short*)(ws + (16 << 20));   // 25.6 MB
    unsigned short* h1b = (unsigned short*)((char*)hb0 + bfTab);
    unsigned short* mnb = (unsigned short*)((char*)h1b + bfTab);
    float* out = (float*)d_out;

    // ---- 1: fused prep (bucket histogram + weight swizzle + bf16 cast) ----
    prep_fused<<<PB + 32 + CAST_BLOCKS, 256, 0, stream>>>(
        dst, gHist, nE, chunk, (const float4*)emb, hb0, n4,
        W1s, W1n, wt1, W2s, W2n, wt2);

    // ---- 2-4: CSR build ----
    scan_one<<<1, 1024, 0, stream>>>(gHist);
    part_scatter<<<PB, 1024, 0, stream>>>(src, dst, gHist, ebuf, nE, chunk);
    bucket_csr<<<nActB, 1024, 0, stream>>>(ebuf, gHist, off, csr, nE);

    // ---- 5-8: layers (separate gather + gemm; see R4 post-mortem) ----
    const int gatherBlocks = (N_NODES_C + 3) / 4;    // 25000
    const int gemmBlocks = (N_NODES_C + 127) / 128;  // 782

    gather_mean_w2<<<gatherBlocks, 256, 0, stream>>>(hb0, csr, off, mnb, N_NODES_C);
    sage_gemm_mfma<<<gemmBlocks, 256, 0, stream>>>(hb0, mnb, wt1, b1, h1b, N_NODES_C, 1);

    gather_mean_w2<<<gatherBlocks, 256, 0, stream>>>(h1b, csr, off, mnb, N_NODES_C);
    sage_gemm_mfma<<<gemmBlocks, 256, 0, stream>>>(h1b, mnb, wt2, b2, out, N_NODES_C, 0);
}

// Round 5
// 336.140 us; speedup vs baseline: 1.1464x; 1.1464x over previous
//
#include <hip/hip_runtime.h>
#include <hip/hip_bf16.h>

#define N_NODES_C 100000
#define FEATS 128
#define SH 10             // bucket shift: 1024 nodes per bucket
#define NBK 128           // padded bucket count (active: 98)
#define PB  256           // partition blocks
#define CAST_BLOCKS 12500 // (100000*128/4)/256

typedef unsigned int uint32;
typedef __bf16 bf16_t;
typedef bf16_t bf16x8 __attribute__((ext_vector_type(8)));
typedef float f32x4 __attribute__((ext_vector_type(4)));

union Frag { uint4 u; bf16x8 v; };

__device__ __forceinline__ unsigned short f32_to_bf16_bits(float f) {
    uint32 u = __float_as_uint(f);
    u += 0x7fffu + ((u >> 16) & 1u);   // round-to-nearest-even (finite values)
    return (unsigned short)(u >> 16);
}
__device__ __forceinline__ float bf16_lo(uint32 p) { return __uint_as_float(p << 16); }
__device__ __forceinline__ float bf16_hi(uint32 p) { return __uint_as_float(p & 0xffff0000u); }

// ---------------- Fused prep: part_count + wtprep x2 + cast ----------------
__global__ __launch_bounds__(256) void prep_fused(
    const int* __restrict__ dst, int* __restrict__ gHist, int nE, int chunk,
    const float4* __restrict__ emb4, unsigned short* __restrict__ hb0, int n4,
    const float* __restrict__ W1s, const float* __restrict__ W1n, unsigned short* __restrict__ wt1,
    const float* __restrict__ W2s, const float* __restrict__ W2n, unsigned short* __restrict__ wt2)
{
    __shared__ int h[NBK];
    const int b = blockIdx.x;
    const int tid = threadIdx.x;

    if (b < PB) {
        // --- bucket histogram over this block's edge chunk ---
        if (tid < NBK) h[tid] = 0;
        __syncthreads();
        const int b0 = b * chunk;
        const int e1 = min(b0 + chunk, nE);
        for (int e = b0 + tid; e < e1; e += 256)
            atomicAdd(&h[dst[e] >> SH], 1);
        __syncthreads();
        if (tid < NBK) gHist[tid * PB + b] = h[tid];
    } else if (b < PB + 32) {
        // --- weight pre-swizzle into B-fragment order ---
        // wt[(f*64+l)*8+j] = W[k][n], f=nt*8+ks, n=nt*16+(l&15), k=ks*32+(l>>4)*8+j
        const int which = (b - PB) >> 4;                 // 0 -> layer1, 1 -> layer2
        const float* Ws = which ? W2s : W1s;
        const float* Wn = which ? W2n : W1n;
        unsigned short* wt = which ? wt2 : wt1;
        int gid = ((b - PB) & 15) * 256 + tid;           // 0..4095
        int frag = gid >> 6, lane = gid & 63;
        int nt = frag >> 3, ks = frag & 7;
        int n = nt * 16 + (lane & 15);
        int kbase = ks * 32 + (lane >> 4) * 8;
        union { unsigned short s[8]; uint4 u; } o;
#pragma unroll
        for (int j = 0; j < 8; ++j) {
            int k = kbase + j;
            float v = (k < 128) ? Ws[(size_t)k * FEATS + n] : Wn[(size_t)(k - 128) * FEATS + n];
            o.s[j] = f32_to_bf16_bits(v);
        }
        *(uint4*)(wt + (size_t)gid * 8) = o.u;
    } else {
        // --- fp32 -> bf16 node-table cast (row-major [N][128]) ---
        int i = (b - PB - 32) * 256 + tid;
        if (i >= n4) return;
        float4 v = emb4[i];
        union { unsigned short s[4]; uint2 u; } o;
        o.s[0] = f32_to_bf16_bits(v.x);
        o.s[1] = f32_to_bf16_bits(v.y);
        o.s[2] = f32_to_bf16_bits(v.z);
        o.s[3] = f32_to_bf16_bits(v.w);
        *(uint2*)(hb0 + (size_t)i * 4) = o.u;
    }
}

// ---------------- One-dispatch exclusive scan of gHist (32768 ints) ----------------
__global__ __launch_bounds__(1024) void scan_one(int* __restrict__ g) {
    __shared__ int ss[1024];
    const int tid = threadIdx.x;
    const int base = tid * 32;
    int pref[32];
    int sum = 0;
#pragma unroll
    for (int j = 0; j < 32; ++j) {
        int v = g[base + j];
        pref[j] = sum;
        sum += v;
    }
    ss[tid] = sum;
    __syncthreads();
    for (int d = 1; d < 1024; d <<= 1) {
        int t = (tid >= d) ? ss[tid - d] : 0;
        __syncthreads();
        ss[tid] += t;
        __syncthreads();
    }
    int ex = ss[tid] - sum;
#pragma unroll
    for (int j = 0; j < 32; ++j)
        g[base + j] = ex + pref[j];
}

// ---------------- P2: scatter packed (src | localdst<<17) into bucketed ebuf ----------------
// 1024 threads/block: 256 blocks -> 16 waves/CU of TLP for this latency-bound scatter.
__global__ __launch_bounds__(1024) void part_scatter(const int* __restrict__ src,
                                                     const int* __restrict__ dst,
                                                     const int* __restrict__ gScan,
                                                     uint32* __restrict__ ebuf,
                                                     int nE, int chunk) {
    __shared__ int cur[NBK];
    const int tid = threadIdx.x;
    if (tid < NBK) cur[tid] = gScan[tid * PB + blockIdx.x];
    __syncthreads();
    const int b0 = blockIdx.x * chunk;
    const int e1 = min(b0 + chunk, nE);
    for (int e = b0 + tid; e < e1; e += 1024) {
        int d = dst[e];
        int pos = atomicAdd(&cur[d >> SH], 1);
        ebuf[pos] = (uint32)src[e] | ((uint32)(d & ((1 << SH) - 1)) << 17);
    }
}

// ---------------- P3: per-bucket CSR finalize ----------------
// csr stores src*256 = byte offset of the node's 256-B feature row (src < 2^17, fits 25 bits).
__global__ __launch_bounds__(1024) void bucket_csr(const uint32* __restrict__ ebuf,
                                                   const int* __restrict__ gScan,
                                                   int* __restrict__ off,
                                                   int* __restrict__ csr,
                                                   int nE) {
    __shared__ int cnt[1 << SH];
    __shared__ int ss[1 << SH];
    const int b = blockIdx.x;
    const int tid = threadIdx.x;
    const int start = gScan[b * PB];
    const int end = gScan[(b + 1) * PB];
    const int nodeBase = b << SH;
    cnt[tid] = 0;
    __syncthreads();
    for (int e = start + tid; e < end; e += 1024)
        atomicAdd(&cnt[ebuf[e] >> 17], 1);
    __syncthreads();
    int own = cnt[tid];
    ss[tid] = own;
    __syncthreads();
    for (int d = 1; d < 1024; d <<= 1) {
        int t = (tid >= d) ? ss[tid - d] : 0;
        __syncthreads();
        ss[tid] += t;
        __syncthreads();
    }
    int ex = ss[tid] - own;
    cnt[tid] = ex;                     // becomes placement cursor
    int node = nodeBase + tid;
    if (node < N_NODES_C) off[node] = start + ex;
    if (b == gridDim.x - 1 && tid == 0) off[N_NODES_C] = nE;
    __syncthreads();
    for (int e = start + tid; e < end; e += 1024) {
        uint32 p = ebuf[e];
        int pos = atomicAdd(&cnt[p >> 17], 1);
        csr[start + pos] = (int)((p & 0x1FFFFu) << 8);   // byte offset of src row
    }
}

// ---------------- Gather (mean aggregation over bf16 table) ----------------
// 4 nodes per 256-thread block; one wave per node; uint2 (8 B) per lane so one
// load instruction covers TWO edges' 256-B rows (lanes 0-31 = even edge,
// 32-63 = odd edge). Even/odd partials combined with shfl_xor(32) at the end.
// csr holds byte offsets (src*256): per-load address = one 64-bit add.
// Main loop unrolled to 16 edges (8 loads in flight) for MLP (latency-bound).
// One wave per node keeps 100K waves in flight (do not re-fuse with GEMM).
__global__ __launch_bounds__(256) void gather_mean_w2(const unsigned short* __restrict__ hb,
                                                      const int* __restrict__ csrB,
                                                      const int* __restrict__ off,
                                                      unsigned short* __restrict__ meanb,
                                                      int nNodes) {
    const int node = blockIdx.x * 4 + (threadIdx.x >> 6);
    const int lane = threadIdx.x & 63;
    if (node >= nNodes) return;
    const int start = __builtin_amdgcn_readfirstlane(off[node]);
    const int end   = __builtin_amdgcn_readfirstlane(off[node + 1]);
    const int half = lane >> 5;                 // which edge of a pair
    const int c = lane & 31;                    // uint2 column within 256-B row
    const char* base = (const char*)hb + (size_t)(c * 8);
    float a0 = 0.f, a1 = 0.f, a2 = 0.f, a3 = 0.f;
    int e = start;
    for (; e + 16 <= end; e += 16) {
        const int o0  = csrB[e + 0],  o1  = csrB[e + 1],  o2  = csrB[e + 2],  o3  = csrB[e + 3];
        const int o4  = csrB[e + 4],  o5  = csrB[e + 5],  o6  = csrB[e + 6],  o7  = csrB[e + 7];
        const int o8  = csrB[e + 8],  o9  = csrB[e + 9],  o10 = csrB[e + 10], o11 = csrB[e + 11];
        const int o12 = csrB[e + 12], o13 = csrB[e + 13], o14 = csrB[e + 14], o15 = csrB[e + 15];
        const uint2 u0 = *(const uint2*)(base + (size_t)(half ? o1  : o0));
        const uint2 u1 = *(const uint2*)(base + (size_t)(half ? o3  : o2));
        const uint2 u2 = *(const uint2*)(base + (size_t)(half ? o5  : o4));
        const uint2 u3 = *(const uint2*)(base + (size_t)(half ? o7  : o6));
        const uint2 u4 = *(const uint2*)(base + (size_t)(half ? o9  : o8));
        const uint2 u5 = *(const uint2*)(base + (size_t)(half ? o11 : o10));
        const uint2 u6 = *(const uint2*)(base + (size_t)(half ? o13 : o12));
        const uint2 u7 = *(const uint2*)(base + (size_t)(half ? o15 : o14));
        a0 += bf16_lo(u0.x); a1 += bf16_hi(u0.x); a2 += bf16_lo(u0.y); a3 += bf16_hi(u0.y);
        a0 += bf16_lo(u1.x); a1 += bf16_hi(u1.x); a2 += bf16_lo(u1.y); a3 += bf16_hi(u1.y);
        a0 += bf16_lo(u2.x); a1 += bf16_hi(u2.x); a2 += bf16_lo(u2.y); a3 += bf16_hi(u2.y);
        a0 += bf16_lo(u3.x); a1 += bf16_hi(u3.x); a2 += bf16_lo(u3.y); a3 += bf16_hi(u3.y);
        a0 += bf16_lo(u4.x); a1 += bf16_hi(u4.x); a2 += bf16_lo(u4.y); a3 += bf16_hi(u4.y);
        a0 += bf16_lo(u5.x); a1 += bf16_hi(u5.x); a2 += bf16_lo(u5.y); a3 += bf16_hi(u5.y);
        a0 += bf16_lo(u6.x); a1 += bf16_hi(u6.x); a2 += bf16_lo(u6.y); a3 += bf16_hi(u6.y);
        a0 += bf16_lo(u7.x); a1 += bf16_hi(u7.x); a2 += bf16_lo(u7.y); a3 += bf16_hi(u7.y);
    }
    if (e + 8 <= end) {
        const int o0 = csrB[e + 0], o1 = csrB[e + 1], o2 = csrB[e + 2], o3 = csrB[e + 3];
        const int o4 = csrB[e + 4], o5 = csrB[e + 5], o6 = csrB[e + 6], o7 = csrB[e + 7];
        const uint2 u0 = *(const uint2*)(base + (size_t)(half ? o1 : o0));
        const uint2 u1 = *(const uint2*)(base + (size_t)(half ? o3 : o2));
        const uint2 u2 = *(const uint2*)(base + (size_t)(half ? o5 : o4));
        const uint2 u3 = *(const uint2*)(base + (size_t)(half ? o7 : o6));
        a0 += bf16_lo(u0.x); a1 += bf16_hi(u0.x); a2 += bf16_lo(u0.y); a3 += bf16_hi(u0.y);
        a0 += bf16_lo(u1.x); a1 += bf16_hi(u1.x); a2 += bf16_lo(u1.y); a3 += bf16_hi(u1.y);
        a0 += bf16_lo(u2.x); a1 += bf16_hi(u2.x); a2 += bf16_lo(u2.y); a3 += bf16_hi(u2.y);
        a0 += bf16_lo(u3.x); a1 += bf16_hi(u3.x); a2 += bf16_lo(u3.y); a3 += bf16_hi(u3.y);
        e += 8;
    }
    if (e + 4 <= end) {
        const int o0 = csrB[e + 0], o1 = csrB[e + 1], o2 = csrB[e + 2], o3 = csrB[e + 3];
        const uint2 u0 = *(const uint2*)(base + (size_t)(half ? o1 : o0));
        const uint2 u1 = *(const uint2*)(base + (size_t)(half ? o3 : o2));
        a0 += bf16_lo(u0.x); a1 += bf16_hi(u0.x); a2 += bf16_lo(u0.y); a3 += bf16_hi(u0.y);
        a0 += bf16_lo(u1.x); a1 += bf16_hi(u1.x); a2 += bf16_lo(u1.y); a3 += bf16_hi(u1.y);
        e += 4;
    }
    if (e + 2 <= end) {
        const int o0 = csrB[e + 0], o1 = csrB[e + 1];
        const uint2 u = *(const uint2*)(base + (size_t)(half ? o1 : o0));
        a0 += bf16_lo(u.x); a1 += bf16_hi(u.x); a2 += bf16_lo(u.y); a3 += bf16_hi(u.y);
        e += 2;
    }
    if (e < end && half == 0) {
        const uint2 u = *(const uint2*)(base + (size_t)csrB[e]);
        a0 += bf16_lo(u.x); a1 += bf16_hi(u.x); a2 += bf16_lo(u.y); a3 += bf16_hi(u.y);
    }
    // combine even-edge / odd-edge partial sums held in lane pairs (l, l^32)
    a0 += __shfl_xor(a0, 32);
    a1 += __shfl_xor(a1, 32);
    a2 += __shfl_xor(a2, 32);
    a3 += __shfl_xor(a3, 32);
    const int deg = end - start;
    const float invd = (deg > 0) ? (1.f / (float)deg) : 0.f;
    if (half == 0) {
        uint2 o;
        o.x = ((uint32)f32_to_bf16_bits(a1 * invd) << 16) | (uint32)f32_to_bf16_bits(a0 * invd);
        o.y = ((uint32)f32_to_bf16_bits(a3 * invd) << 16) | (uint32)f32_to_bf16_bits(a2 * invd);
        ((uint2*)meanb)[(size_t)node * 32 + c] = o;
    }
}

// ---------------- MFMA SAGE GEMM (LDS-free) ----------------
// Per wave: 16-row stripe x 128 cols, K=256 = [HB | MB].
// NOTE (R4 post-mortem): 32-row/wave variant (a[16]+acc[16] live) exceeded the
// register budget -> scratch round-trips -> 2x slower (MfmaUtil 3.6%, all idle).
// Keep 16-row: a[8]+acc[8] fits; grid 1563 gives 6 waves/SIMD of TLP.
__global__ __launch_bounds__(256) void sage_gemm_mfma(const unsigned short* __restrict__ HB,
                                                      const unsigned short* __restrict__ MB,
                                                      const unsigned short* __restrict__ WT,
                                                      const float* __restrict__ bias,
                                                      void* __restrict__ OUTP,
                                                      int nNodes, int mode) {
    const int wave = threadIdx.x >> 6;
    const int lane = threadIdx.x & 63;
    const int waveBase = blockIdx.x * 64 + wave * 16;
    const int m = lane & 15;
    const int quad = lane >> 4;

    int arow = waveBase + m;
    if (arow >= nNodes) arow = nNodes - 1;           // clamp loads; stores guarded below
    const uint4* hrow = (const uint4*)(HB + (size_t)arow * FEATS);
    const uint4* mrow = (const uint4*)(MB + (size_t)arow * FEATS);

    Frag a[8];
#pragma unroll
    for (int ks = 0; ks < 4; ++ks) a[ks].u = hrow[ks * 4 + quad];
#pragma unroll
    for (int ks = 0; ks < 4; ++ks) a[ks + 4].u = mrow[ks * 4 + quad];

    const uint4* wt4 = (const uint4*)WT;
    f32x4 acc[8];
#pragma unroll
    for (int nt = 0; nt < 8; ++nt) acc[nt] = (f32x4){0.f, 0.f, 0.f, 0.f};

#pragma unroll
    for (int ks = 0; ks < 8; ++ks) {
#pragma unroll
        for (int nt = 0; nt < 8; ++nt) {
            Frag b;
            b.u = wt4[(size_t)(nt * 8 + ks) * 64 + lane];
            acc[nt] = __builtin_amdgcn_mfma_f32_16x16x32_bf16(a[ks].v, b.v, acc[nt], 0, 0, 0);
        }
    }

#pragma unroll
    for (int nt = 0; nt < 8; ++nt) {
        const int col = nt * 16 + m;
        const float bv = bias[col];
#pragma unroll
        for (int r = 0; r < 4; ++r) {
            const int grow = waveBase + quad * 4 + r;   // C/D: row=(lane>>4)*4+reg, col=lane&15
            if (grow >= nNodes) continue;
            float v = acc[nt][r] + bv;
            if (mode) {
                v = v > 0.f ? v : 0.2f * v;
                ((unsigned short*)OUTP)[(size_t)grow * FEATS + col] = f32_to_bf16_bits(v);
            } else {
                ((float*)OUTP)[(size_t)grow * FEATS + col] = v;
            }
        }
    }
}

extern "C" void kernel_launch(void* const* d_in, const int* in_sizes, int n_in,
                              void* d_out, int out_size, void* d_ws, size_t ws_size,
                              hipStream_t stream) {
    const float* emb = (const float*)d_in[0];
    const float* W1s = (const float*)d_in[1];
    const float* W1n = (const float*)d_in[2];
    const float* b1  = (const float*)d_in[3];
    const float* W2s = (const float*)d_in[4];
    const float* W2n = (const float*)d_in[5];
    const float* b2  = (const float*)d_in[6];
    const int*   edg = (const int*)d_in[7];

    const int nE = in_sizes[7] / 2;
    const int* src = edg;
    const int* dst = edg + nE;

    const int chunk = (nE + PB - 1) / PB;            // 6250
    const int nActB = (N_NODES_C + (1 << SH) - 1) >> SH;   // 98
    const int n4 = N_NODES_C * FEATS / 4;            // 3,200,000

    const size_t bfTab = (size_t)N_NODES_C * FEATS * sizeof(unsigned short);  // 25.6 MB

    char* ws = (char*)d_ws;
    int* off      = (int*)(ws);                      // 400 KB + 4
    int* gHist    = (int*)(ws + (512 << 10));        // 128 KB
    int* csr      = (int*)(ws + (1 << 20));          // 6.4 MB
    uint32* ebuf  = (uint32*)(ws + (8 << 20));       // 6.4 MB
    unsigned short* wt1 = (unsigned short*)(ws + (15 << 20));   // 64 KB
    unsigned short* wt2 = (unsigned short*)(ws + (15 << 20) + (64 << 10));
    unsigned short* hb0 = (unsigned short*)(ws + (16 << 20));   // 25.6 MB
    unsigned short* h1b = (unsigned short*)((char*)hb0 + bfTab);
    unsigned short* mnb = (unsigned short*)((char*)h1b + bfTab);
    float* out = (float*)d_out;

    // ---- 1: fused prep (bucket histogram + weight swizzle + bf16 cast) ----
    prep_fused<<<PB + 32 + CAST_BLOCKS, 256, 0, stream>>>(
        dst, gHist, nE, chunk, (const float4*)emb, hb0, n4,
        W1s, W1n, wt1, W2s, W2n, wt2);

    // ---- 2-4: CSR build ----
    scan_one<<<1, 1024, 0, stream>>>(gHist);
    part_scatter<<<PB, 1024, 0, stream>>>(src, dst, gHist, ebuf, nE, chunk);
    bucket_csr<<<nActB, 1024, 0, stream>>>(ebuf, gHist, off, csr, nE);

    // ---- 5-8: layers (separate gather + gemm) ----
    const int gatherBlocks = (N_NODES_C + 3) / 4;    // 25000
    const int gemmBlocks = (N_NODES_C + 63) / 64;    // 1563

    gather_mean_w2<<<gatherBlocks, 256, 0, stream>>>(hb0, csr, off, mnb, N_NODES_C);
    sage_gemm_mfma<<<gemmBlocks, 256, 0, stream>>>(hb0, mnb, wt1, b1, h1b, N_NODES_C, 1);

    gather_mean_w2<<<gatherBlocks, 256, 0, stream>>>(h1b, csr, off, mnb, N_NODES_C);
    sage_gemm_mfma<<<gemmBlocks, 256, 0, stream>>>(h1b, mnb, wt2, b2, out, N_NODES_C, 0);
}

// Round 6
// 324.300 us; speedup vs baseline: 1.1882x; 1.0365x over previous
//
#include <hip/hip_runtime.h>
#include <hip/hip_bf16.h>

#define N_NODES_C 100000
#define FEATS 128
#define SH 10             // bucket shift: 1024 nodes per bucket
#define NBK 128           // padded bucket count (active: 98)
#define PB  256           // partition blocks
#define CAST_BLOCKS 12500 // (100000*128/4)/256

typedef unsigned int uint32;
typedef __bf16 bf16_t;
typedef bf16_t bf16x8 __attribute__((ext_vector_type(8)));
typedef float f32x4 __attribute__((ext_vector_type(4)));

union Frag { uint4 u; bf16x8 v; };

__device__ __forceinline__ unsigned short f32_to_bf16_bits(float f) {
    uint32 u = __float_as_uint(f);
    u += 0x7fffu + ((u >> 16) & 1u);   // round-to-nearest-even (finite values)
    return (unsigned short)(u >> 16);
}
__device__ __forceinline__ float bf16_lo(uint32 p) { return __uint_as_float(p << 16); }
__device__ __forceinline__ float bf16_hi(uint32 p) { return __uint_as_float(p & 0xffff0000u); }

// ---------------- Fused prep: part_count + wtprep x2 + cast ----------------
__global__ __launch_bounds__(256) void prep_fused(
    const int* __restrict__ dst, int* __restrict__ gHist, int nE, int chunk,
    const float4* __restrict__ emb4, unsigned short* __restrict__ hb0, int n4,
    const float* __restrict__ W1s, const float* __restrict__ W1n, unsigned short* __restrict__ wt1,
    const float* __restrict__ W2s, const float* __restrict__ W2n, unsigned short* __restrict__ wt2)
{
    __shared__ int h[NBK];
    const int b = blockIdx.x;
    const int tid = threadIdx.x;

    if (b < PB) {
        // --- bucket histogram over this block's edge chunk ---
        if (tid < NBK) h[tid] = 0;
        __syncthreads();
        const int b0 = b * chunk;
        const int e1 = min(b0 + chunk, nE);
        for (int e = b0 + tid; e < e1; e += 256)
            atomicAdd(&h[dst[e] >> SH], 1);
        __syncthreads();
        if (tid < NBK) gHist[tid * PB + b] = h[tid];
    } else if (b < PB + 32) {
        // --- weight pre-swizzle into B-fragment order ---
        // wt[(f*64+l)*8+j] = W[k][n], f=nt*8+ks, n=nt*16+(l&15), k=ks*32+(l>>4)*8+j
        const int which = (b - PB) >> 4;                 // 0 -> layer1, 1 -> layer2
        const float* Ws = which ? W2s : W1s;
        const float* Wn = which ? W2n : W1n;
        unsigned short* wt = which ? wt2 : wt1;
        int gid = ((b - PB) & 15) * 256 + tid;           // 0..4095
        int frag = gid >> 6, lane = gid & 63;
        int nt = frag >> 3, ks = frag & 7;
        int n = nt * 16 + (lane & 15);
        int kbase = ks * 32 + (lane >> 4) * 8;
        union { unsigned short s[8]; uint4 u; } o;
#pragma unroll
        for (int j = 0; j < 8; ++j) {
            int k = kbase + j;
            float v = (k < 128) ? Ws[(size_t)k * FEATS + n] : Wn[(size_t)(k - 128) * FEATS + n];
            o.s[j] = f32_to_bf16_bits(v);
        }
        *(uint4*)(wt + (size_t)gid * 8) = o.u;
    } else {
        // --- fp32 -> bf16 node-table cast (row-major [N][128]) ---
        int i = (b - PB - 32) * 256 + tid;
        if (i >= n4) return;
        float4 v = emb4[i];
        union { unsigned short s[4]; uint2 u; } o;
        o.s[0] = f32_to_bf16_bits(v.x);
        o.s[1] = f32_to_bf16_bits(v.y);
        o.s[2] = f32_to_bf16_bits(v.z);
        o.s[3] = f32_to_bf16_bits(v.w);
        *(uint2*)(hb0 + (size_t)i * 4) = o.u;
    }
}

// ---------------- One-dispatch exclusive scan of gHist (32768 ints) ----------------
__global__ __launch_bounds__(1024) void scan_one(int* __restrict__ g) {
    __shared__ int ss[1024];
    const int tid = threadIdx.x;
    const int base = tid * 32;
    int pref[32];
    int sum = 0;
#pragma unroll
    for (int j = 0; j < 32; ++j) {
        int v = g[base + j];
        pref[j] = sum;
        sum += v;
    }
    ss[tid] = sum;
    __syncthreads();
    for (int d = 1; d < 1024; d <<= 1) {
        int t = (tid >= d) ? ss[tid - d] : 0;
        __syncthreads();
        ss[tid] += t;
        __syncthreads();
    }
    int ex = ss[tid] - sum;
#pragma unroll
    for (int j = 0; j < 32; ++j)
        g[base + j] = ex + pref[j];
}

// ---------------- P2: scatter packed (src | localdst<<17) into bucketed ebuf ----------------
// 1024 threads/block: 256 blocks -> 16 waves/CU of TLP for this latency-bound scatter.
__global__ __launch_bounds__(1024) void part_scatter(const int* __restrict__ src,
                                                     const int* __restrict__ dst,
                                                     const int* __restrict__ gScan,
                                                     uint32* __restrict__ ebuf,
                                                     int nE, int chunk) {
    __shared__ int cur[NBK];
    const int tid = threadIdx.x;
    if (tid < NBK) cur[tid] = gScan[tid * PB + blockIdx.x];
    __syncthreads();
    const int b0 = blockIdx.x * chunk;
    const int e1 = min(b0 + chunk, nE);
    for (int e = b0 + tid; e < e1; e += 1024) {
        int d = dst[e];
        int pos = atomicAdd(&cur[d >> SH], 1);
        ebuf[pos] = (uint32)src[e] | ((uint32)(d & ((1 << SH) - 1)) << 17);
    }
}

// ---------------- P3: per-bucket CSR finalize ----------------
// csr stores src*256 = byte offset of the node's 256-B feature row (src < 2^17, fits 25 bits).
__global__ __launch_bounds__(1024) void bucket_csr(const uint32* __restrict__ ebuf,
                                                   const int* __restrict__ gScan,
                                                   int* __restrict__ off,
                                                   int* __restrict__ csr,
                                                   int nE) {
    __shared__ int cnt[1 << SH];
    __shared__ int ss[1 << SH];
    const int b = blockIdx.x;
    const int tid = threadIdx.x;
    const int start = gScan[b * PB];
    const int end = gScan[(b + 1) * PB];
    const int nodeBase = b << SH;
    cnt[tid] = 0;
    __syncthreads();
    for (int e = start + tid; e < end; e += 1024)
        atomicAdd(&cnt[ebuf[e] >> 17], 1);
    __syncthreads();
    int own = cnt[tid];
    ss[tid] = own;
    __syncthreads();
    for (int d = 1; d < 1024; d <<= 1) {
        int t = (tid >= d) ? ss[tid - d] : 0;
        __syncthreads();
        ss[tid] += t;
        __syncthreads();
    }
    int ex = ss[tid] - own;
    cnt[tid] = ex;                     // becomes placement cursor
    int node = nodeBase + tid;
    if (node < N_NODES_C) off[node] = start + ex;
    if (b == gridDim.x - 1 && tid == 0) off[N_NODES_C] = nE;
    __syncthreads();
    for (int e = start + tid; e < end; e += 1024) {
        uint32 p = ebuf[e];
        int pos = atomicAdd(&cnt[p >> 17], 1);
        csr[start + pos] = (int)((p & 0x1FFFFu) << 8);   // byte offset of src row
    }
}

// ---------------- Gather (mean aggregation over bf16 table) ----------------
// 4 nodes per 256-thread block; one wave per node; uint4 (16 B) per lane so one
// load instruction covers FOUR edges' 256-B rows (lane>>4 = edge slot, lane&15 =
// uint4 column). Quad partials combined with shfl_xor(16)+shfl_xor(32).
// csr holds byte offsets (src*256): per-load address = one 64-bit add.
// Main loop = 32 edges (8 uint4 loads in flight). FETCH is at the compulsory
// 181 MB floor; this version halves load-issue + address VALU per byte vs uint2.
// One wave per node keeps 100K waves in flight (do not re-fuse with GEMM).
__global__ __launch_bounds__(256) void gather_mean_w4(const unsigned short* __restrict__ hb,
                                                      const int* __restrict__ csrB,
                                                      const int* __restrict__ off,
                                                      unsigned short* __restrict__ meanb,
                                                      int nNodes) {
    const int node = blockIdx.x * 4 + (threadIdx.x >> 6);
    const int lane = threadIdx.x & 63;
    if (node >= nNodes) return;
    const int start = __builtin_amdgcn_readfirstlane(off[node]);
    const int end   = __builtin_amdgcn_readfirstlane(off[node + 1]);
    const int g = lane >> 4;                 // edge slot within quad
    const int c = lane & 15;                 // uint4 column within 256-B row
    const char* base = (const char*)hb + (size_t)(c * 16);
    float a0 = 0.f, a1 = 0.f, a2 = 0.f, a3 = 0.f, a4 = 0.f, a5 = 0.f, a6 = 0.f, a7 = 0.f;

#define QSEL(pA, pB, pC, pD) ((g & 2) ? ((g & 1) ? (pD) : (pC)) : ((g & 1) ? (pB) : (pA)))
#define ACC(u) { a0 += bf16_lo((u).x); a1 += bf16_hi((u).x); a2 += bf16_lo((u).y); a3 += bf16_hi((u).y); \
                 a4 += bf16_lo((u).z); a5 += bf16_hi((u).z); a6 += bf16_lo((u).w); a7 += bf16_hi((u).w); }

    int e = start;
    for (; e + 32 <= end; e += 32) {
        const int p0  = csrB[e + 0],  p1  = csrB[e + 1],  p2  = csrB[e + 2],  p3  = csrB[e + 3];
        const int p4  = csrB[e + 4],  p5  = csrB[e + 5],  p6  = csrB[e + 6],  p7  = csrB[e + 7];
        const int p8  = csrB[e + 8],  p9  = csrB[e + 9],  p10 = csrB[e + 10], p11 = csrB[e + 11];
        const int p12 = csrB[e + 12], p13 = csrB[e + 13], p14 = csrB[e + 14], p15 = csrB[e + 15];
        const int p16 = csrB[e + 16], p17 = csrB[e + 17], p18 = csrB[e + 18], p19 = csrB[e + 19];
        const int p20 = csrB[e + 20], p21 = csrB[e + 21], p22 = csrB[e + 22], p23 = csrB[e + 23];
        const int p24 = csrB[e + 24], p25 = csrB[e + 25], p26 = csrB[e + 26], p27 = csrB[e + 27];
        const int p28 = csrB[e + 28], p29 = csrB[e + 29], p30 = csrB[e + 30], p31 = csrB[e + 31];
        const uint4 u0 = *(const uint4*)(base + (size_t)QSEL(p0,  p1,  p2,  p3));
        const uint4 u1 = *(const uint4*)(base + (size_t)QSEL(p4,  p5,  p6,  p7));
        const uint4 u2 = *(const uint4*)(base + (size_t)QSEL(p8,  p9,  p10, p11));
        const uint4 u3 = *(const uint4*)(base + (size_t)QSEL(p12, p13, p14, p15));
        const uint4 u4 = *(const uint4*)(base + (size_t)QSEL(p16, p17, p18, p19));
        const uint4 u5 = *(const uint4*)(base + (size_t)QSEL(p20, p21, p22, p23));
        const uint4 u6 = *(const uint4*)(base + (size_t)QSEL(p24, p25, p26, p27));
        const uint4 u7 = *(const uint4*)(base + (size_t)QSEL(p28, p29, p30, p31));
        ACC(u0); ACC(u1); ACC(u2); ACC(u3); ACC(u4); ACC(u5); ACC(u6); ACC(u7);
    }
    if (e + 16 <= end) {
        const int p0  = csrB[e + 0],  p1  = csrB[e + 1],  p2  = csrB[e + 2],  p3  = csrB[e + 3];
        const int p4  = csrB[e + 4],  p5  = csrB[e + 5],  p6  = csrB[e + 6],  p7  = csrB[e + 7];
        const int p8  = csrB[e + 8],  p9  = csrB[e + 9],  p10 = csrB[e + 10], p11 = csrB[e + 11];
        const int p12 = csrB[e + 12], p13 = csrB[e + 13], p14 = csrB[e + 14], p15 = csrB[e + 15];
        const uint4 u0 = *(const uint4*)(base + (size_t)QSEL(p0,  p1,  p2,  p3));
        const uint4 u1 = *(const uint4*)(base + (size_t)QSEL(p4,  p5,  p6,  p7));
        const uint4 u2 = *(const uint4*)(base + (size_t)QSEL(p8,  p9,  p10, p11));
        const uint4 u3 = *(const uint4*)(base + (size_t)QSEL(p12, p13, p14, p15));
        ACC(u0); ACC(u1); ACC(u2); ACC(u3);
        e += 16;
    }
    if (e + 8 <= end) {
        const int p0 = csrB[e + 0], p1 = csrB[e + 1], p2 = csrB[e + 2], p3 = csrB[e + 3];
        const int p4 = csrB[e + 4], p5 = csrB[e + 5], p6 = csrB[e + 6], p7 = csrB[e + 7];
        const uint4 u0 = *(const uint4*)(base + (size_t)QSEL(p0, p1, p2, p3));
        const uint4 u1 = *(const uint4*)(base + (size_t)QSEL(p4, p5, p6, p7));
        ACC(u0); ACC(u1);
        e += 8;
    }
    if (e + 4 <= end) {
        const int p0 = csrB[e + 0], p1 = csrB[e + 1], p2 = csrB[e + 2], p3 = csrB[e + 3];
        const uint4 u = *(const uint4*)(base + (size_t)QSEL(p0, p1, p2, p3));
        ACC(u);
        e += 4;
    }
    {
        const int rem = end - e;             // 0..3, wave-uniform
        if (rem > 0 && g < rem) {
            const int p0 = csrB[e];
            const int p1 = (rem > 1) ? csrB[e + 1] : p0;
            const int p2 = (rem > 2) ? csrB[e + 2] : p0;
            const int o = (g == 0) ? p0 : ((g == 1) ? p1 : p2);
            const uint4 u = *(const uint4*)(base + (size_t)o);
            ACC(u);
        }
    }
#undef QSEL
#undef ACC
    // combine the 4 edge-slot partial sums held in lane groups (c, c+16, c+32, c+48)
    a0 += __shfl_xor(a0, 16); a0 += __shfl_xor(a0, 32);
    a1 += __shfl_xor(a1, 16); a1 += __shfl_xor(a1, 32);
    a2 += __shfl_xor(a2, 16); a2 += __shfl_xor(a2, 32);
    a3 += __shfl_xor(a3, 16); a3 += __shfl_xor(a3, 32);
    a4 += __shfl_xor(a4, 16); a4 += __shfl_xor(a4, 32);
    a5 += __shfl_xor(a5, 16); a5 += __shfl_xor(a5, 32);
    a6 += __shfl_xor(a6, 16); a6 += __shfl_xor(a6, 32);
    a7 += __shfl_xor(a7, 16); a7 += __shfl_xor(a7, 32);
    const int deg = end - start;
    const float invd = (deg > 0) ? (1.f / (float)deg) : 0.f;
    if (g == 0) {
        uint4 o;
        o.x = ((uint32)f32_to_bf16_bits(a1 * invd) << 16) | (uint32)f32_to_bf16_bits(a0 * invd);
        o.y = ((uint32)f32_to_bf16_bits(a3 * invd) << 16) | (uint32)f32_to_bf16_bits(a2 * invd);
        o.z = ((uint32)f32_to_bf16_bits(a5 * invd) << 16) | (uint32)f32_to_bf16_bits(a4 * invd);
        o.w = ((uint32)f32_to_bf16_bits(a7 * invd) << 16) | (uint32)f32_to_bf16_bits(a6 * invd);
        ((uint4*)meanb)[(size_t)node * 16 + c] = o;
    }
}

// ---------------- MFMA SAGE GEMM (LDS-staged weights) ----------------
// 512 threads = 8 waves x 16-row stripes (128 rows/block), K=256 = [HB | MB].
// WT (64 KB) staged in LDS once per block; B-frag reads become contiguous
// conflict-free ds_read_b128 instead of each wave re-streaming 64 KB from L2
// (was 400 MB of L2->VGPR traffic across the grid).
// NOTE (R4 post-mortem): 32-row/wave (a[16]+acc[16] live) blew the register
// budget -> scratch -> 2x slower. Keep the 16-row register shape.
__global__ __launch_bounds__(512) void sage_gemm_mfma(const unsigned short* __restrict__ HB,
                                                      const unsigned short* __restrict__ MB,
                                                      const unsigned short* __restrict__ WT,
                                                      const float* __restrict__ bias,
                                                      void* __restrict__ OUTP,
                                                      int nNodes, int mode) {
    __shared__ uint4 wtl[4096];                       // 64 KB
    const int tid = threadIdx.x;
    const uint4* wt4 = (const uint4*)WT;
#pragma unroll
    for (int i = 0; i < 8; ++i)
        wtl[i * 512 + tid] = wt4[i * 512 + tid];

    const int wave = tid >> 6;
    const int lane = tid & 63;
    const int waveBase = blockIdx.x * 128 + wave * 16;
    const int m = lane & 15;
    const int quad = lane >> 4;

    int arow = waveBase + m;
    if (arow >= nNodes) arow = nNodes - 1;           // clamp loads; stores guarded below
    const uint4* hrow = (const uint4*)(HB + (size_t)arow * FEATS);
    const uint4* mrow = (const uint4*)(MB + (size_t)arow * FEATS);

    Frag a[8];
#pragma unroll
    for (int ks = 0; ks < 4; ++ks) a[ks].u = hrow[ks * 4 + quad];
#pragma unroll
    for (int ks = 0; ks < 4; ++ks) a[ks + 4].u = mrow[ks * 4 + quad];

    __syncthreads();

    f32x4 acc[8];
#pragma unroll
    for (int nt = 0; nt < 8; ++nt) acc[nt] = (f32x4){0.f, 0.f, 0.f, 0.f};

#pragma unroll
    for (int ks = 0; ks < 8; ++ks) {
#pragma unroll
        for (int nt = 0; nt < 8; ++nt) {
            Frag b;
            b.u = wtl[(nt * 8 + ks) * 64 + lane];
            acc[nt] = __builtin_amdgcn_mfma_f32_16x16x32_bf16(a[ks].v, b.v, acc[nt], 0, 0, 0);
        }
    }

#pragma unroll
    for (int nt = 0; nt < 8; ++nt) {
        const int col = nt * 16 + m;
        const float bv = bias[col];
#pragma unroll
        for (int r = 0; r < 4; ++r) {
            const int grow = waveBase + quad * 4 + r;   // C/D: row=(lane>>4)*4+reg, col=lane&15
            if (grow >= nNodes) continue;
            float v = acc[nt][r] + bv;
            if (mode) {
                v = v > 0.f ? v : 0.2f * v;
                ((unsigned short*)OUTP)[(size_t)grow * FEATS + col] = f32_to_bf16_bits(v);
            } else {
                ((float*)OUTP)[(size_t)grow * FEATS + col] = v;
            }
        }
    }
}

extern "C" void kernel_launch(void* const* d_in, const int* in_sizes, int n_in,
                              void* d_out, int out_size, void* d_ws, size_t ws_size,
                              hipStream_t stream) {
    const float* emb = (const float*)d_in[0];
    const float* W1s = (const float*)d_in[1];
    const float* W1n = (const float*)d_in[2];
    const float* b1  = (const float*)d_in[3];
    const float* W2s = (const float*)d_in[4];
    const float* W2n = (const float*)d_in[5];
    const float* b2  = (const float*)d_in[6];
    const int*   edg = (const int*)d_in[7];

    const int nE = in_sizes[7] / 2;
    const int* src = edg;
    const int* dst = edg + nE;

    const int chunk = (nE + PB - 1) / PB;            // 6250
    const int nActB = (N_NODES_C + (1 << SH) - 1) >> SH;   // 98
    const int n4 = N_NODES_C * FEATS / 4;            // 3,200,000

    const size_t bfTab = (size_t)N_NODES_C * FEATS * sizeof(unsigned short);  // 25.6 MB

    char* ws = (char*)d_ws;
    int* off      = (int*)(ws);                      // 400 KB + 4
    int* gHist    = (int*)(ws + (512 << 10));        // 128 KB
    int* csr      = (int*)(ws + (1 << 20));          // 6.4 MB
    uint32* ebuf  = (uint32*)(ws + (8 << 20));       // 6.4 MB
    unsigned short* wt1 = (unsigned short*)(ws + (15 << 20));   // 64 KB
    unsigned short* wt2 = (unsigned short*)(ws + (15 << 20) + (64 << 10));
    unsigned short* hb0 = (unsigned short*)(ws + (16 << 20));   // 25.6 MB
    unsigned short* h1b = (unsigned short*)((char*)hb0 + bfTab);
    unsigned short* mnb = (unsigned short*)((char*)h1b + bfTab);
    float* out = (float*)d_out;

    // ---- 1: fused prep (bucket histogram + weight swizzle + bf16 cast) ----
    prep_fused<<<PB + 32 + CAST_BLOCKS, 256, 0, stream>>>(
        dst, gHist, nE, chunk, (const float4*)emb, hb0, n4,
        W1s, W1n, wt1, W2s, W2n, wt2);

    // ---- 2-4: CSR build ----
    scan_one<<<1, 1024, 0, stream>>>(gHist);
    part_scatter<<<PB, 1024, 0, stream>>>(src, dst, gHist, ebuf, nE, chunk);
    bucket_csr<<<nActB, 1024, 0, stream>>>(ebuf, gHist, off, csr, nE);

    // ---- 5-8: layers (separate gather + gemm) ----
    const int gatherBlocks = (N_NODES_C + 3) / 4;    // 25000
    const int gemmBlocks = (N_NODES_C + 127) / 128;  // 782

    gather_mean_w4<<<gatherBlocks, 256, 0, stream>>>(hb0, csr, off, mnb, N_NODES_C);
    sage_gemm_mfma<<<gemmBlocks, 512, 0, stream>>>(hb0, mnb, wt1, b1, h1b, N_NODES_C, 1);

    gather_mean_w4<<<gatherBlocks, 256, 0, stream>>>(h1b, csr, off, mnb, N_NODES_C);
    sage_gemm_mfma<<<gemmBlocks, 512, 0, stream>>>(h1b, mnb, wt2, b2, out, N_NODES_C, 0);
}